// Round 5
// baseline (273.090 us; speedup 1.0000x reference)
//
#include <hip/hip_runtime.h>

typedef short v8s __attribute__((ext_vector_type(8)));
typedef float v4f __attribute__((ext_vector_type(4)));
using u16 = unsigned short;

// ============================================================================
// TILED LAYOUTS (all bf16). Every hot GLOBAL LOAD is base + lane*16B (1KB,
// fully coalesced) -- confirmed r3: attn 134->94.7us from addressing alone.
// r4 lesson: q-tile height = K/V reuse. 32-row tiles doubled L2 traffic and
// cancelled the TLP gain. Stay at 64-row tiles.
// r5 theory: v6's residual ~4x gap vs issue-model is the __syncthreads
// vmcnt(0) drain killing the K prefetch every chunk -> raw barrier.
//
// TILE16 (activations/out, M x 256): fragment tile = 16 rows x 256 ch.
//   idx(row,ch) = ((row>>4)*8 + (ch>>5))*512 + (((ch>>3)&3)*16 + (row&15))*8 + (ch&7)
// WTILE (weights, 256x256):
//   idx(k,n) = ((n>>4)*8 + (k>>5))*512 + (((k>>3)&3)*16 + (n&15))*8 + (k&7)
// VTILE (V^T, per batch): tile(chunk, chblk, ks) as B-operand of PV.
//
// QSCALE = log2(e)/16 folded into Wq/bq so attn does exp2f(sc) directly.
// ============================================================================
#define QSCALE 0.09016844f

__device__ __forceinline__ u16 f2b(float f) {
  union { float f; unsigned u; } v; v.f = f;
  unsigned r = v.u + 0x7FFFu + ((v.u >> 16) & 1u);
  return (u16)(r >> 16);
}

// ---------------- LayerNorm + bf16 casts (tiled outputs) ----------------
__global__ void ln_prep(const float* __restrict__ x, const float* __restrict__ ctx,
                        const float* __restrict__ gamma, const float* __restrict__ beta,
                        float* __restrict__ xn_f, u16* __restrict__ xn_b,
                        u16* __restrict__ ctx_b)
{
  const int tid = threadIdx.x;
  const int wid = tid >> 6, lane = tid & 63;
  const int row = blockIdx.x * 4 + wid;
  const size_t tidx = ((size_t)(row >> 4) * 8 + (lane >> 3)) * 512 +
                      (((lane >> 1) & 3) * 16 + (row & 15)) * 8 + (lane & 1) * 4;
  if (blockIdx.y == 0) {
    const float4 xv = *(const float4*)(x + (size_t)row * 256 + lane * 4);
    float s1 = xv.x + xv.y + xv.z + xv.w;
    float s2 = xv.x*xv.x + xv.y*xv.y + xv.z*xv.z + xv.w*xv.w;
#pragma unroll
    for (int m = 32; m >= 1; m >>= 1) {
      s1 += __shfl_xor(s1, m);
      s2 += __shfl_xor(s2, m);
    }
    const float mu  = s1 * (1.0f/256.0f);
    const float var = s2 * (1.0f/256.0f) - mu*mu;
    const float rs  = rsqrtf(var + 1e-3f);
    const float4 g = *(const float4*)(gamma + lane*4);
    const float4 b = *(const float4*)(beta  + lane*4);
    float4 y;
    y.x = (xv.x-mu)*rs*g.x + b.x;
    y.y = (xv.y-mu)*rs*g.y + b.y;
    y.z = (xv.z-mu)*rs*g.z + b.z;
    y.w = (xv.w-mu)*rs*g.w + b.w;
    *(float4*)(xn_f + (size_t)row*256 + lane*4) = y;
    ushort4 yb; yb.x=f2b(y.x); yb.y=f2b(y.y); yb.z=f2b(y.z); yb.w=f2b(y.w);
    *(ushort4*)(xn_b + tidx) = yb;
  } else {
    const float4 cv = *(const float4*)(ctx + (size_t)row * 256 + lane * 4);
    ushort4 cb; cb.x=f2b(cv.x); cb.y=f2b(cv.y); cb.z=f2b(cv.z); cb.w=f2b(cv.w);
    *(ushort4*)(ctx_b + tidx) = cb;
  }
}

// ---------------- weight transpose + bf16 cast into WTILE ----------------
__global__ void wtrans(const float* __restrict__ wq, const float* __restrict__ wk,
                       const float* __restrict__ wv, const float* __restrict__ wp,
                       u16* __restrict__ tq, u16* __restrict__ tk,
                       u16* __restrict__ tv, u16* __restrict__ tp)
{
  const float* src; u16* dst; float scl = 1.0f;
  switch (blockIdx.y) {
    case 0:  src = wq; dst = tq; scl = QSCALE; break;
    case 1:  src = wk; dst = tk; break;
    case 2:  src = wv; dst = tv; break;
    default: src = wp; dst = tp; break;
  }
  const int t  = threadIdx.x;
  const int kk = blockIdx.x * 16 + (t >> 4);
  const int n0 = (t & 15) * 16;
  const size_t base = (size_t)((t & 15) * 8 + (kk >> 5)) * 512 +
                      ((kk >> 3) & 3) * 16 * 8 + (kk & 7);
#pragma unroll
  for (int j = 0; j < 16; j++)
    dst[base + (size_t)j * 8] = f2b(src[(size_t)kk * 256 + n0 + j] * scl);
}

// ---------------- q/k/v GEMM: 64 rows PER WAVE (W read once per 64 rows) ----
// 2-wave blocks, 128 rows/block, grid (128, 3). W L2-traffic / 4 vs r4.
__global__ __launch_bounds__(128) void gemm_qkv(
    const u16* __restrict__ xn_b, const u16* __restrict__ ctx_b,
    const u16* __restrict__ wqt, const u16* __restrict__ wkt, const u16* __restrict__ wvt,
    const float* __restrict__ bq, const float* __restrict__ bk, const float* __restrict__ bv,
    u16* __restrict__ qo, u16* __restrict__ ko, u16* __restrict__ vto)
{
  const int mode = blockIdx.y;
  const u16* A; const u16* Wt; const float* bias;
  if (mode == 0)      { A = xn_b;  Wt = wqt; bias = bq; }
  else if (mode == 1) { A = ctx_b; Wt = wkt; bias = bk; }
  else                { A = ctx_b; Wt = wvt; bias = bv; }
  const float bscale = (mode == 0) ? QSCALE : 1.0f;
  const int wid = threadIdx.x >> 6, lane = threadIdx.x & 63;
  const int lm = lane & 15, q4 = lane >> 4;
  const int m0 = blockIdx.x * 128 + wid * 64;   // this wave's 64-row base
  // A fragments for 4 row-tiles (held: 128 VGPR)
  v8s af[4][8];
#pragma unroll
  for (int rt = 0; rt < 4; rt++) {
    const u16* abase = A + (size_t)((m0 >> 4) + rt) * 4096 + lane * 8;
#pragma unroll
    for (int kf = 0; kf < 8; kf++) af[rt][kf] = *(const v8s*)(abase + kf * 512);
  }
#pragma unroll
  for (int ct = 0; ct < 16; ct++) {
    const int c = ct * 16 + lm;
    const u16* wbase = Wt + (size_t)ct * 4096 + lane * 8;
    v8s wf[8];
#pragma unroll
    for (int kf = 0; kf < 8; kf++) wf[kf] = *(const v8s*)(wbase + kf * 512);
    v4f acc[4];
#pragma unroll
    for (int rt = 0; rt < 4; rt++) acc[rt] = (v4f){0.f, 0.f, 0.f, 0.f};
    // 4 independent rt chains = ILP 4
#pragma unroll
    for (int kf = 0; kf < 8; kf++)
#pragma unroll
      for (int rt = 0; rt < 4; rt++)
        acc[rt] = __builtin_amdgcn_mfma_f32_16x16x32_bf16(af[rt][kf], wf[kf], acc[rt], 0, 0, 0);
    const float bb = bias[c] * bscale;
#pragma unroll
    for (int rt = 0; rt < 4; rt++) {
      const int row16 = m0 + rt * 16;
      if (mode == 2) {
        const int b = row16 >> 12;
        const int chunk = (row16 & 4095) >> 6;
        const int kic = (row16 & 63) + q4 * 4;
        const int ks = kic >> 5;
        const int q4p = (kic >> 3) & 3;
        const size_t idx = ((size_t)(b * 64 + chunk) * 32 + (c >> 4) * 2 + ks) * 512 +
                           (q4p * 16 + (c & 15)) * 8 + (q4 & 1) * 4;
        ushort4 pk;
        pk.x = f2b(acc[rt][0] + bb); pk.y = f2b(acc[rt][1] + bb);
        pk.z = f2b(acc[rt][2] + bb); pk.w = f2b(acc[rt][3] + bb);
        *(ushort4*)(vto + idx) = pk;
      } else {
        u16* out = (mode == 0) ? qo : ko;
        const size_t base = ((size_t)(row16 >> 4) * 8 + (c >> 5)) * 512 +
                            (((c >> 3) & 3) * 16 + q4 * 4) * 8 + (c & 7);
#pragma unroll
        for (int r = 0; r < 4; r++)
          out[base + (size_t)r * 8] = f2b(acc[rt][r] + bb);
      }
    }
  }
}

// ---------------- flash-style attention, v8 ----------------
// = r3's proven 94.7us kernel (64 Q-rows, 4 waves, coalesced tiled loads,
//   V-first / mfma(K,Q) / K-prefetch schedule) with two changes:
// 1. RAW BARRIER: s_waitcnt lgkmcnt(0) + s_barrier instead of __syncthreads.
//    __syncthreads drains vmcnt(0) -> kills the K prefetch every chunk.
//    P visibility only needs LDS waits; V/K consumption is protected by the
//    compiler's counted register-dep vmcnt (V older than K -> K stays in
//    flight across the barrier).
// 2. XCD-batch affinity (proven r4: FETCH 70->20MB): bid&7 = XCD,
//    batch = (bid&7)>>1 -> each XCD serves one batch (4MB = L2).
__global__ __launch_bounds__(256, 1) void attn_kernel(
    const u16* __restrict__ q, const u16* __restrict__ k,
    const u16* __restrict__ vt, u16* __restrict__ ao)
{
  __shared__ u16 P[2][64][72];   // [buf][q][key] bf16, 18.4 KB
  __shared__ float Lp[4][64];
  __shared__ float Lt[64];
  const int bid  = blockIdx.x;
  const int b    = (bid & 7) >> 1;                 // batch -> XCD pair
  const int qblk = ((bid >> 3) << 1) | (bid & 1);  // [0,64)
  const int tid = threadIdx.x;
  const int w   = tid >> 6, lane = tid & 63;
  const int lm  = lane & 15, q4 = lane >> 4;
  const int m0  = qblk * 64;
  const u16* qb = q  + (size_t)b * 1048576;
  const u16* kb = k  + (size_t)b * 1048576;
  const u16* vb = vt + (size_t)b * 1048576;

  // Q fragments for 4 q-tiles (coalesced 1KB loads)
  v8s qf[4][8];
#pragma unroll
  for (int qt = 0; qt < 4; qt++) {
    const u16* qbase = qb + (size_t)((m0 >> 4) + qt) * 4096 + lane * 8;
#pragma unroll
    for (int kf = 0; kf < 8; kf++) qf[qt][kf] = *(const v8s*)(qbase + kf * 512);
  }

  v4f o[4][4];
#pragma unroll
  for (int qt = 0; qt < 4; qt++)
#pragma unroll
    for (int ct = 0; ct < 4; ct++) o[qt][ct] = (v4f){0.f, 0.f, 0.f, 0.f};
  float lsum[4] = {0.f, 0.f, 0.f, 0.f};

  // K fragments for chunk 0 (this wave's 16-key strip)
  v8s kfr[8];
  {
    const u16* kbase = kb + (size_t)w * 4096 + lane * 8;
#pragma unroll
    for (int kf = 0; kf < 8; kf++) kfr[kf] = *(const v8s*)(kbase + kf * 512);
  }

  for (int s0 = 0; s0 < 4096; s0 += 64) {
    const int pb = (s0 >> 6) & 1;
    const int chunk = s0 >> 6;
    // V loads for this chunk, issued first: phase A + exp cover their latency
    v8s vfr[4][2];
#pragma unroll
    for (int ct = 0; ct < 4; ct++) {
      const u16* vbase = vb + ((size_t)chunk * 32 + (w * 4 + ct) * 2) * 512 + lane * 8;
      vfr[ct][0] = *(const v8s*)(vbase);
      vfr[ct][1] = *(const v8s*)(vbase + 512);
    }
    // phase A: S^T strips via mfma(K, Q) -> lane: q-row qt*16+lm, keys w*16+q4*4+r
    v4f sc[4];
#pragma unroll
    for (int qt = 0; qt < 4; qt++) sc[qt] = (v4f){0.f, 0.f, 0.f, 0.f};
#pragma unroll
    for (int kf = 0; kf < 8; kf++)
#pragma unroll
      for (int qt = 0; qt < 4; qt++)
        sc[qt] = __builtin_amdgcn_mfma_f32_16x16x32_bf16(kfr[kf], qf[qt][kf], sc[qt], 0, 0, 0);
    // K prefetch for next chunk (consumed next chunk; stays in flight across
    // the raw barrier -- that's the whole point)
    {
      const int sn = (s0 + 64) & 4095;
      const u16* kbase = kb + (size_t)((sn >> 4) + w) * 4096 + lane * 8;
#pragma unroll
      for (int kf = 0; kf < 8; kf++) kfr[kf] = *(const v8s*)(kbase + kf * 512);
    }
    // exp2 (scale pre-folded into q) -> packed bf16 -> one b64 write per q-tile
#pragma unroll
    for (int qt = 0; qt < 4; qt++) {
      const float e0 = exp2f(sc[qt][0]);
      const float e1 = exp2f(sc[qt][1]);
      const float e2 = exp2f(sc[qt][2]);
      const float e3 = exp2f(sc[qt][3]);
      lsum[qt] += (e0 + e1) + (e2 + e3);
      unsigned d0, d1;
      asm("v_cvt_pk_bf16_f32 %0, %1, %2" : "=v"(d0) : "v"(e0), "v"(e1));
      asm("v_cvt_pk_bf16_f32 %0, %1, %2" : "=v"(d1) : "v"(e2), "v"(e3));
      uint2 pk; pk.x = d0; pk.y = d1;
      *(uint2*)(&P[pb][qt * 16 + lm][w * 16 + q4 * 4]) = pk;
    }
    // LDS-visibility-only barrier: global prefetches stay in flight
    asm volatile("s_waitcnt lgkmcnt(0)" ::: "memory");
    __builtin_amdgcn_s_barrier();
    // phase B: O[64q x 64ch(w)] += P * V (vmcnt for vfr is counted, K in flight)
#pragma unroll
    for (int qt = 0; qt < 4; qt++) {
      const v8s pf0 = *(const v8s*)(&P[pb][qt * 16 + lm][q4 * 8]);
      const v8s pf1 = *(const v8s*)(&P[pb][qt * 16 + lm][32 + q4 * 8]);
#pragma unroll
      for (int ct = 0; ct < 4; ct++) {
        o[qt][ct] = __builtin_amdgcn_mfma_f32_16x16x32_bf16(pf0, vfr[ct][0], o[qt][ct], 0, 0, 0);
        o[qt][ct] = __builtin_amdgcn_mfma_f32_16x16x32_bf16(pf1, vfr[ct][1], o[qt][ct], 0, 0, 0);
      }
    }
  }

  // l: per-lane lsum covers keys {w*16+q4*4..+3} of q-row qt*16+lm.
#pragma unroll
  for (int qt = 0; qt < 4; qt++) {
    float t = lsum[qt];
    t += __shfl_xor(t, 16);
    t += __shfl_xor(t, 32);
    lsum[qt] = t;
  }
  if (q4 == 0) {
#pragma unroll
    for (int qt = 0; qt < 4; qt++) Lp[w][qt * 16 + lm] = lsum[qt];
  }
  __syncthreads();
  if (tid < 64) Lt[tid] = Lp[0][tid] + Lp[1][tid] + Lp[2][tid] + Lp[3][tid];
  __syncthreads();

  // TILE16 output write
  const int rstrip0 = (b * 4096 + m0) >> 4;
#pragma unroll
  for (int qt = 0; qt < 4; qt++)
#pragma unroll
    for (int r = 0; r < 4; r++) {
      const float linv = 1.0f / Lt[qt * 16 + q4 * 4 + r];
#pragma unroll
      for (int ct = 0; ct < 4; ct++) {
        const int ch = w * 64 + ct * 16 + lm;
        const size_t idx = ((size_t)(rstrip0 + qt) * 8 + (ch >> 5)) * 512 +
                           (((ch >> 3) & 3) * 16 + q4 * 4 + r) * 8 + (ch & 7);
        ao[idx] = f2b(o[qt][ct][r] * linv);
      }
    }
}

// ---------------- proj GEMM: 64 rows per wave + bias + residual ----------
__global__ __launch_bounds__(128) void gemm_proj(
    const u16* __restrict__ A, const u16* __restrict__ Wt, const float* __restrict__ bias,
    const float* __restrict__ xn_f, float* __restrict__ out)
{
  const int wid = threadIdx.x >> 6, lane = threadIdx.x & 63;
  const int lm = lane & 15, q4 = lane >> 4;
  const int m0 = blockIdx.x * 128 + wid * 64;
  v8s af[4][8];
#pragma unroll
  for (int rt = 0; rt < 4; rt++) {
    const u16* abase = A + (size_t)((m0 >> 4) + rt) * 4096 + lane * 8;
#pragma unroll
    for (int kf = 0; kf < 8; kf++) af[rt][kf] = *(const v8s*)(abase + kf * 512);
  }
#pragma unroll
  for (int ct = 0; ct < 16; ct++) {
    const int c = ct * 16 + lm;
    const u16* wbase = Wt + (size_t)ct * 4096 + lane * 8;
    v8s wf[8];
#pragma unroll
    for (int kf = 0; kf < 8; kf++) wf[kf] = *(const v8s*)(wbase + kf * 512);
    v4f acc[4];
#pragma unroll
    for (int rt = 0; rt < 4; rt++) acc[rt] = (v4f){0.f, 0.f, 0.f, 0.f};
#pragma unroll
    for (int kf = 0; kf < 8; kf++)
#pragma unroll
      for (int rt = 0; rt < 4; rt++)
        acc[rt] = __builtin_amdgcn_mfma_f32_16x16x32_bf16(af[rt][kf], wf[kf], acc[rt], 0, 0, 0);
    const float bb = bias[c];
#pragma unroll
    for (int rt = 0; rt < 4; rt++)
#pragma unroll
      for (int r = 0; r < 4; r++) {
        const size_t idx = (size_t)(m0 + rt * 16 + q4 * 4 + r) * 256 + c;
        out[idx] = xn_f[idx] + acc[rt][r] + bb;
      }
  }
}

extern "C" void kernel_launch(void* const* d_in, const int* in_sizes, int n_in,
                              void* d_out, int out_size, void* d_ws, size_t ws_size,
                              hipStream_t stream)
{
  (void)in_sizes; (void)n_in; (void)out_size; (void)ws_size;
  const float* inputs  = (const float*)d_in[0];
  const float* context = (const float*)d_in[1];
  const float* Wq = (const float*)d_in[2];
  const float* bq = (const float*)d_in[3];
  const float* Wk = (const float*)d_in[4];
  const float* bk = (const float*)d_in[5];
  const float* Wv = (const float*)d_in[6];
  const float* bv = (const float*)d_in[7];
  const float* Wp = (const float*)d_in[8];
  const float* bp = (const float*)d_in[9];
  const float* gamma = (const float*)d_in[10];
  const float* beta  = (const float*)d_in[11];
  float* out = (float*)d_out;

  char* p = (char*)d_ws;
  float* xn_f = (float*)p; p += (size_t)16384 * 256 * 4;
  u16* xn_b   = (u16*)p;   p += (size_t)16384 * 256 * 2;
  u16* ctx_b  = (u16*)p;   p += (size_t)16384 * 256 * 2;
  u16* qbuf   = (u16*)p;   p += (size_t)16384 * 256 * 2;
  u16* kbuf   = (u16*)p;   p += (size_t)16384 * 256 * 2;
  u16* vtbuf  = (u16*)p;   p += (size_t)16384 * 256 * 2;
  u16* wqt = (u16*)p; p += (size_t)256 * 256 * 2;
  u16* wkt = (u16*)p; p += (size_t)256 * 256 * 2;
  u16* wvt = (u16*)p; p += (size_t)256 * 256 * 2;
  u16* wpt = (u16*)p; p += (size_t)256 * 256 * 2;
  u16* aobuf = xn_b;  // xn_b dead after gemm_qkv

  ln_prep<<<dim3(4096, 2), 256, 0, stream>>>(inputs, context, gamma, beta, xn_f, xn_b, ctx_b);
  wtrans<<<dim3(16, 4), 256, 0, stream>>>(Wq, Wk, Wv, Wp, wqt, wkt, wvt, wpt);
  gemm_qkv<<<dim3(128, 3), 128, 0, stream>>>(xn_b, ctx_b, wqt, wkt, wvt, bq, bk, bv, qbuf, kbuf, vtbuf);
  attn_kernel<<<dim3(256), 256, 0, stream>>>(qbuf, kbuf, vtbuf, aobuf);
  gemm_proj<<<dim3(128), 128, 0, stream>>>(aobuf, wpt, bp, xn_f, out);
}

// Round 6
// 216.652 us; speedup vs baseline: 1.2605x; 1.2605x over previous
//
#include <hip/hip_runtime.h>

typedef short v8s __attribute__((ext_vector_type(8)));
typedef float v4f __attribute__((ext_vector_type(4)));
using u16 = unsigned short;

// ============================================================================
// TILED LAYOUTS (all bf16). Every hot GLOBAL LOAD is base + lane*16B (1KB,
// fully coalesced) -- confirmed r3: attn 134->94.7us from addressing alone.
// r4 lesson: q-tile height = K/V reuse. 32-row tiles doubled L2 traffic and
// cancelled the TLP gain. Stay at 64-row tiles.
// r5 lessons: raw-barrier = null (vmcnt-drain theory dead); XCD affinity cuts
// FETCH 3.4x but not time (attn not HBM-bound); 64-rows/wave GEMM = -50us
// (killed parallelism). attn is issue-starved at 1 wave/SIMD ->
// r6: 8 waves/block, SAME 64-row tile, 128-key chunks = 2 waves/SIMD at
// constant traffic.
//
// TILE16 (activations/out, M x 256): fragment tile = 16 rows x 256 ch.
//   idx(row,ch) = ((row>>4)*8 + (ch>>5))*512 + (((ch>>3)&3)*16 + (row&15))*8 + (ch&7)
// WTILE (weights, 256x256):
//   idx(k,n) = ((n>>4)*8 + (k>>5))*512 + (((k>>3)&3)*16 + (n&15))*8 + (k&7)
// VTILE (V^T, per batch): tile(chunk64, chblk, ks32) as B-operand of PV.
//
// QSCALE = log2(e)/16 folded into Wq/bq so attn does exp2f(sc) directly.
// ============================================================================
#define QSCALE 0.09016844f

__device__ __forceinline__ u16 f2b(float f) {
  union { float f; unsigned u; } v; v.f = f;
  unsigned r = v.u + 0x7FFFu + ((v.u >> 16) & 1u);
  return (u16)(r >> 16);
}

// ---------------- LayerNorm + bf16 casts (tiled outputs) ----------------
__global__ void ln_prep(const float* __restrict__ x, const float* __restrict__ ctx,
                        const float* __restrict__ gamma, const float* __restrict__ beta,
                        float* __restrict__ xn_f, u16* __restrict__ xn_b,
                        u16* __restrict__ ctx_b)
{
  const int tid = threadIdx.x;
  const int wid = tid >> 6, lane = tid & 63;
  const int row = blockIdx.x * 4 + wid;
  const size_t tidx = ((size_t)(row >> 4) * 8 + (lane >> 3)) * 512 +
                      (((lane >> 1) & 3) * 16 + (row & 15)) * 8 + (lane & 1) * 4;
  if (blockIdx.y == 0) {
    const float4 xv = *(const float4*)(x + (size_t)row * 256 + lane * 4);
    float s1 = xv.x + xv.y + xv.z + xv.w;
    float s2 = xv.x*xv.x + xv.y*xv.y + xv.z*xv.z + xv.w*xv.w;
#pragma unroll
    for (int m = 32; m >= 1; m >>= 1) {
      s1 += __shfl_xor(s1, m);
      s2 += __shfl_xor(s2, m);
    }
    const float mu  = s1 * (1.0f/256.0f);
    const float var = s2 * (1.0f/256.0f) - mu*mu;
    const float rs  = rsqrtf(var + 1e-3f);
    const float4 g = *(const float4*)(gamma + lane*4);
    const float4 b = *(const float4*)(beta  + lane*4);
    float4 y;
    y.x = (xv.x-mu)*rs*g.x + b.x;
    y.y = (xv.y-mu)*rs*g.y + b.y;
    y.z = (xv.z-mu)*rs*g.z + b.z;
    y.w = (xv.w-mu)*rs*g.w + b.w;
    *(float4*)(xn_f + (size_t)row*256 + lane*4) = y;
    ushort4 yb; yb.x=f2b(y.x); yb.y=f2b(y.y); yb.z=f2b(y.z); yb.w=f2b(y.w);
    *(ushort4*)(xn_b + tidx) = yb;
  } else {
    const float4 cv = *(const float4*)(ctx + (size_t)row * 256 + lane * 4);
    ushort4 cb; cb.x=f2b(cv.x); cb.y=f2b(cv.y); cb.z=f2b(cv.z); cb.w=f2b(cv.w);
    *(ushort4*)(ctx_b + tidx) = cb;
  }
}

// ---------------- weight transpose + bf16 cast into WTILE ----------------
__global__ void wtrans(const float* __restrict__ wq, const float* __restrict__ wk,
                       const float* __restrict__ wv, const float* __restrict__ wp,
                       u16* __restrict__ tq, u16* __restrict__ tk,
                       u16* __restrict__ tv, u16* __restrict__ tp)
{
  const float* src; u16* dst; float scl = 1.0f;
  switch (blockIdx.y) {
    case 0:  src = wq; dst = tq; scl = QSCALE; break;
    case 1:  src = wk; dst = tk; break;
    case 2:  src = wv; dst = tv; break;
    default: src = wp; dst = tp; break;
  }
  const int t  = threadIdx.x;
  const int kk = blockIdx.x * 16 + (t >> 4);
  const int n0 = (t & 15) * 16;
  const size_t base = (size_t)((t & 15) * 8 + (kk >> 5)) * 512 +
                      ((kk >> 3) & 3) * 16 * 8 + (kk & 7);
#pragma unroll
  for (int j = 0; j < 16; j++)
    dst[base + (size_t)j * 8] = f2b(src[(size_t)kk * 256 + n0 + j] * scl);
}

// ---------------- q/k/v GEMM (r4 version: proven 125us non-attn path) ------
__global__ __launch_bounds__(256) void gemm_qkv(
    const u16* __restrict__ xn_b, const u16* __restrict__ ctx_b,
    const u16* __restrict__ wqt, const u16* __restrict__ wkt, const u16* __restrict__ wvt,
    const float* __restrict__ bq, const float* __restrict__ bk, const float* __restrict__ bv,
    u16* __restrict__ qo, u16* __restrict__ ko, u16* __restrict__ vto)
{
  const int mode = blockIdx.y;
  const u16* A; const u16* Wt; const float* bias;
  if (mode == 0)      { A = xn_b;  Wt = wqt; bias = bq; }
  else if (mode == 1) { A = ctx_b; Wt = wkt; bias = bk; }
  else                { A = ctx_b; Wt = wvt; bias = bv; }
  const float bscale = (mode == 0) ? QSCALE : 1.0f;
  const int wid = threadIdx.x >> 6, lane = threadIdx.x & 63;
  const int lm = lane & 15, q4 = lane >> 4;
  const int m0 = blockIdx.x * 64 + wid * 16;
  const u16* abase = A + (size_t)(m0 >> 4) * 4096 + lane * 8;
  v8s af[8];
#pragma unroll
  for (int kf = 0; kf < 8; kf++) af[kf] = *(const v8s*)(abase + kf * 512);
#pragma unroll
  for (int ct = 0; ct < 16; ct++) {
    const int c = ct * 16 + lm;
    const u16* wbase = Wt + (size_t)ct * 4096 + lane * 8;
    v8s wf[8];
#pragma unroll
    for (int kf = 0; kf < 8; kf++) wf[kf] = *(const v8s*)(wbase + kf * 512);
    // 4 independent 2-long chains: breaks the 8-long serial acc dependency
    v4f a0 = {0.f,0.f,0.f,0.f}, a1 = a0, a2 = a0, a3 = a0;
    a0 = __builtin_amdgcn_mfma_f32_16x16x32_bf16(af[0], wf[0], a0, 0, 0, 0);
    a1 = __builtin_amdgcn_mfma_f32_16x16x32_bf16(af[2], wf[2], a1, 0, 0, 0);
    a2 = __builtin_amdgcn_mfma_f32_16x16x32_bf16(af[4], wf[4], a2, 0, 0, 0);
    a3 = __builtin_amdgcn_mfma_f32_16x16x32_bf16(af[6], wf[6], a3, 0, 0, 0);
    a0 = __builtin_amdgcn_mfma_f32_16x16x32_bf16(af[1], wf[1], a0, 0, 0, 0);
    a1 = __builtin_amdgcn_mfma_f32_16x16x32_bf16(af[3], wf[3], a1, 0, 0, 0);
    a2 = __builtin_amdgcn_mfma_f32_16x16x32_bf16(af[5], wf[5], a2, 0, 0, 0);
    a3 = __builtin_amdgcn_mfma_f32_16x16x32_bf16(af[7], wf[7], a3, 0, 0, 0);
    const v4f acc = (a0 + a1) + (a2 + a3);
    const float bb = bias[c] * bscale;
    if (mode == 2) {
      const int b = m0 >> 12;
      const int chunk = (m0 & 4095) >> 6;
      const int kic = (m0 & 63) + q4 * 4;
      const int ks = kic >> 5;
      const int q4p = (kic >> 3) & 3;
      const size_t idx = ((size_t)(b * 64 + chunk) * 32 + (c >> 4) * 2 + ks) * 512 +
                         (q4p * 16 + (c & 15)) * 8 + (q4 & 1) * 4;
      ushort4 pk;
      pk.x = f2b(acc[0] + bb); pk.y = f2b(acc[1] + bb);
      pk.z = f2b(acc[2] + bb); pk.w = f2b(acc[3] + bb);
      *(ushort4*)(vto + idx) = pk;
    } else {
      u16* out = (mode == 0) ? qo : ko;
      const size_t base = ((size_t)(m0 >> 4) * 8 + (c >> 5)) * 512 +
                          (((c >> 3) & 3) * 16 + q4 * 4) * 8 + (c & 7);
#pragma unroll
      for (int r = 0; r < 4; r++)
        out[base + (size_t)r * 8] = f2b(acc[r] + bb);
    }
  }
}

// ---------------- flash-style attention, v9: 8 waves, 2 waves/SIMD ----------
// Same 64-row Q tile (reuse preserved -> total K/V traffic unchanged at 1GB),
// but 512 threads: per 128-key chunk, wave w does phase A on its 16-key strip
// (keys w*16..) and phase B on its 32-channel slab (ch w*32..). 2 waves/SIMD:
// between barriers each SIMD has two independent instruction streams, so one
// wave's load/LDS/exp latency hides under the other's MFMAs. This attacks the
// measured stall (~40% both-pipes-idle at 1 wave/SIMD) that scheduling (v4),
// locality (v5/v8), and barrier (v8) fixes all failed to touch.
__global__ __launch_bounds__(512, 2) void attn_kernel(
    const u16* __restrict__ q, const u16* __restrict__ k,
    const u16* __restrict__ vt, u16* __restrict__ ao)
{
  __shared__ u16 P[2][64][136];   // [buf][q][key128 +8 pad] bf16, 34.8 KB
  __shared__ float Lp[8][64];
  __shared__ float Lt[64];
  const int bid  = blockIdx.x;
  const int b    = (bid & 7) >> 1;                 // batch -> XCD pair
  const int qblk = ((bid >> 3) << 1) | (bid & 1);  // [0,64)
  const int tid  = threadIdx.x;
  const int w    = tid >> 6, lane = tid & 63;      // w in [0,8)
  const int lm   = lane & 15, q4 = lane >> 4;
  const int m0   = qblk * 64;
  const u16* qb = q  + (size_t)b * 1048576;
  const u16* kb = k  + (size_t)b * 1048576;
  const u16* vb = vt + (size_t)b * 1048576;

  // Q fragments for 4 q-tiles (coalesced 1KB loads), held all kernel
  v8s qf[4][8];
#pragma unroll
  for (int qt = 0; qt < 4; qt++) {
    const u16* qbase = qb + (size_t)((m0 >> 4) + qt) * 4096 + lane * 8;
#pragma unroll
    for (int kf = 0; kf < 8; kf++) qf[qt][kf] = *(const v8s*)(qbase + kf * 512);
  }

  v4f o[4][2];   // [qt][ct]: this wave's 32 channels
#pragma unroll
  for (int qt = 0; qt < 4; qt++)
#pragma unroll
    for (int ct = 0; ct < 2; ct++) o[qt][ct] = (v4f){0.f, 0.f, 0.f, 0.f};
  float lsum[4] = {0.f, 0.f, 0.f, 0.f};

  // K fragments for chunk 0: this wave's 16-key strip = strip index w
  v8s kfr[8];
  {
    const u16* kbase = kb + (size_t)w * 4096 + lane * 8;
#pragma unroll
    for (int kf = 0; kf < 8; kf++) kfr[kf] = *(const v8s*)(kbase + kf * 512);
  }

  for (int c128 = 0; c128 < 32; c128++) {
    const int pb = c128 & 1;
    // V loads for this chunk (this wave's 2 ch-blocks x 4 key-slices),
    // issued first so phase A covers their latency. 1KB coalesced each.
    v8s vfr[2][4];
#pragma unroll
    for (int ct = 0; ct < 2; ct++)
#pragma unroll
      for (int j = 0; j < 4; j++) {
        const size_t tile = (size_t)(c128 * 2 + (j >> 1)) * 32 +
                            (w * 2 + ct) * 2 + (j & 1);
        vfr[ct][j] = *(const v8s*)(vb + tile * 512 + lane * 8);
      }
    // phase A: S^T strip via mfma(K, Q) -> lane: q-row qt*16+lm,
    // keys (chunk-rel) w*16 + q4*4 + r
    v4f sc[4];
#pragma unroll
    for (int qt = 0; qt < 4; qt++) sc[qt] = (v4f){0.f, 0.f, 0.f, 0.f};
#pragma unroll
    for (int kf = 0; kf < 8; kf++)
#pragma unroll
      for (int qt = 0; qt < 4; qt++)
        sc[qt] = __builtin_amdgcn_mfma_f32_16x16x32_bf16(kfr[kf], qf[qt][kf], sc[qt], 0, 0, 0);
    // K prefetch for next chunk
    {
      const int nc = (c128 + 1) & 31;
      const u16* kbase = kb + (size_t)(nc * 8 + w) * 4096 + lane * 8;
#pragma unroll
      for (int kf = 0; kf < 8; kf++) kfr[kf] = *(const v8s*)(kbase + kf * 512);
    }
    // exp2 (scale pre-folded into q) -> packed bf16 -> one b64 write per q-tile
#pragma unroll
    for (int qt = 0; qt < 4; qt++) {
      const float e0 = exp2f(sc[qt][0]);
      const float e1 = exp2f(sc[qt][1]);
      const float e2 = exp2f(sc[qt][2]);
      const float e3 = exp2f(sc[qt][3]);
      lsum[qt] += (e0 + e1) + (e2 + e3);
      unsigned d0, d1;
      asm("v_cvt_pk_bf16_f32 %0, %1, %2" : "=v"(d0) : "v"(e0), "v"(e1));
      asm("v_cvt_pk_bf16_f32 %0, %1, %2" : "=v"(d1) : "v"(e2), "v"(e3));
      uint2 pk; pk.x = d0; pk.y = d1;
      *(uint2*)(&P[pb][qt * 16 + lm][w * 16 + q4 * 4]) = pk;
    }
    __syncthreads();
    // phase B: O[64q x 32ch(w)] += P * V over 4 key-slices
#pragma unroll
    for (int qt = 0; qt < 4; qt++) {
      v8s pf[4];
#pragma unroll
      for (int j = 0; j < 4; j++)
        pf[j] = *(const v8s*)(&P[pb][qt * 16 + lm][j * 32 + q4 * 8]);
#pragma unroll
      for (int ct = 0; ct < 2; ct++)
#pragma unroll
        for (int j = 0; j < 4; j++)
          o[qt][ct] = __builtin_amdgcn_mfma_f32_16x16x32_bf16(pf[j], vfr[ct][j], o[qt][ct], 0, 0, 0);
    }
  }

  // l: per-lane lsum covers keys {w*16+q4*4..+3} of q-row qt*16+lm (per chunk).
  // Reduce across q4 groups, then across the 8 waves.
#pragma unroll
  for (int qt = 0; qt < 4; qt++) {
    float t = lsum[qt];
    t += __shfl_xor(t, 16);
    t += __shfl_xor(t, 32);
    lsum[qt] = t;
  }
  if (q4 == 0) {
#pragma unroll
    for (int qt = 0; qt < 4; qt++) Lp[w][qt * 16 + lm] = lsum[qt];
  }
  __syncthreads();
  if (tid < 64) {
    float t = 0.f;
#pragma unroll
    for (int ww = 0; ww < 8; ww++) t += Lp[ww][tid];
    Lt[tid] = t;
  }
  __syncthreads();

  // TILE16 output write: row = b*4096 + m0 + qt*16 + q4*4 + r, ch = w*32+ct*16+lm
  const int rstrip0 = (b * 4096 + m0) >> 4;
#pragma unroll
  for (int qt = 0; qt < 4; qt++)
#pragma unroll
    for (int r = 0; r < 4; r++) {
      const float linv = 1.0f / Lt[qt * 16 + q4 * 4 + r];
#pragma unroll
      for (int ct = 0; ct < 2; ct++) {
        const int ch = w * 32 + ct * 16 + lm;
        const size_t idx = ((size_t)(rstrip0 + qt) * 8 + (ch >> 5)) * 512 +
                           (((ch >> 3) & 3) * 16 + q4 * 4 + r) * 8 + (ch & 7);
        ao[idx] = f2b(o[qt][ct][r] * linv);
      }
    }
}

// ---------------- proj GEMM + bias + residual (r4 version) ----------------
__global__ __launch_bounds__(256) void gemm_proj(
    const u16* __restrict__ A, const u16* __restrict__ Wt, const float* __restrict__ bias,
    const float* __restrict__ xn_f, float* __restrict__ out)
{
  const int wid = threadIdx.x >> 6, lane = threadIdx.x & 63;
  const int lm = lane & 15, q4 = lane >> 4;
  const int m0 = blockIdx.x * 64 + wid * 16;
  const u16* abase = A + (size_t)(m0 >> 4) * 4096 + lane * 8;
  v8s af[8];
#pragma unroll
  for (int kf = 0; kf < 8; kf++) af[kf] = *(const v8s*)(abase + kf * 512);
#pragma unroll
  for (int ct = 0; ct < 16; ct++) {
    const int c = ct * 16 + lm;
    const u16* wbase = Wt + (size_t)ct * 4096 + lane * 8;
    v8s wf[8];
#pragma unroll
    for (int kf = 0; kf < 8; kf++) wf[kf] = *(const v8s*)(wbase + kf * 512);
    v4f a0 = {0.f,0.f,0.f,0.f}, a1 = a0, a2 = a0, a3 = a0;
    a0 = __builtin_amdgcn_mfma_f32_16x16x32_bf16(af[0], wf[0], a0, 0, 0, 0);
    a1 = __builtin_amdgcn_mfma_f32_16x16x32_bf16(af[2], wf[2], a1, 0, 0, 0);
    a2 = __builtin_amdgcn_mfma_f32_16x16x32_bf16(af[4], wf[4], a2, 0, 0, 0);
    a3 = __builtin_amdgcn_mfma_f32_16x16x32_bf16(af[6], wf[6], a3, 0, 0, 0);
    a0 = __builtin_amdgcn_mfma_f32_16x16x32_bf16(af[1], wf[1], a0, 0, 0, 0);
    a1 = __builtin_amdgcn_mfma_f32_16x16x32_bf16(af[3], wf[3], a1, 0, 0, 0);
    a2 = __builtin_amdgcn_mfma_f32_16x16x32_bf16(af[5], wf[5], a2, 0, 0, 0);
    a3 = __builtin_amdgcn_mfma_f32_16x16x32_bf16(af[7], wf[7], a3, 0, 0, 0);
    const v4f acc = (a0 + a1) + (a2 + a3);
    const float bb = bias[c];
#pragma unroll
    for (int r = 0; r < 4; r++) {
      const size_t idx = (size_t)(m0 + q4 * 4 + r) * 256 + c;
      out[idx] = xn_f[idx] + acc[r] + bb;
    }
  }
}

extern "C" void kernel_launch(void* const* d_in, const int* in_sizes, int n_in,
                              void* d_out, int out_size, void* d_ws, size_t ws_size,
                              hipStream_t stream)
{
  (void)in_sizes; (void)n_in; (void)out_size; (void)ws_size;
  const float* inputs  = (const float*)d_in[0];
  const float* context = (const float*)d_in[1];
  const float* Wq = (const float*)d_in[2];
  const float* bq = (const float*)d_in[3];
  const float* Wk = (const float*)d_in[4];
  const float* bk = (const float*)d_in[5];
  const float* Wv = (const float*)d_in[6];
  const float* bv = (const float*)d_in[7];
  const float* Wp = (const float*)d_in[8];
  const float* bp = (const float*)d_in[9];
  const float* gamma = (const float*)d_in[10];
  const float* beta  = (const float*)d_in[11];
  float* out = (float*)d_out;

  char* p = (char*)d_ws;
  float* xn_f = (float*)p; p += (size_t)16384 * 256 * 4;
  u16* xn_b   = (u16*)p;   p += (size_t)16384 * 256 * 2;
  u16* ctx_b  = (u16*)p;   p += (size_t)16384 * 256 * 2;
  u16* qbuf   = (u16*)p;   p += (size_t)16384 * 256 * 2;
  u16* kbuf   = (u16*)p;   p += (size_t)16384 * 256 * 2;
  u16* vtbuf  = (u16*)p;   p += (size_t)16384 * 256 * 2;
  u16* wqt = (u16*)p; p += (size_t)256 * 256 * 2;
  u16* wkt = (u16*)p; p += (size_t)256 * 256 * 2;
  u16* wvt = (u16*)p; p += (size_t)256 * 256 * 2;
  u16* wpt = (u16*)p; p += (size_t)256 * 256 * 2;
  u16* aobuf = xn_b;  // xn_b dead after gemm_qkv

  ln_prep<<<dim3(4096, 2), 256, 0, stream>>>(inputs, context, gamma, beta, xn_f, xn_b, ctx_b);
  wtrans<<<dim3(16, 4), 256, 0, stream>>>(Wq, Wk, Wv, Wp, wqt, wkt, wvt, wpt);
  gemm_qkv<<<dim3(256, 3), 256, 0, stream>>>(xn_b, ctx_b, wqt, wkt, wvt, bq, bk, bv, qbuf, kbuf, vtbuf);
  attn_kernel<<<dim3(256), 512, 0, stream>>>(qbuf, kbuf, vtbuf, aobuf);
  gemm_proj<<<dim3(256), 256, 0, stream>>>(aobuf, wpt, bp, xn_f, out);
}